// Round 13
// baseline (1081.501 us; speedup 1.0000x reference)
//
#include <hip/hip_runtime.h>
#include <stdint.h>

// ---------------------------------------------------------------------------
// 2-layer GCN: relu(gcn(x,W1,b1)) -> batchnorm -> relu(gcn(.,W2,b2))
// n=100000, E=1.6M, f_in=25, hid=128.
// R2: parallel scan (947 -> 681). R6: gemm2 tile + bf16 h (681 -> 593).
// R10: XCD-partitioned direct scatter (593 -> 546).
// R13: propagate was 109us x2 with FETCH=196MB (random gather over 25.6MB h;
//     4MB L2/XCD => ~16% hit). Now: edge lists segmented by SOURCE TILE
//     (8192 nodes = 2.1MB bf16), persistent waves own 13 nodes each with
//     register accumulators, sweep tiles in lockstep-ish order => gather
//     working set ~2 tiles => L2-resident. CSR arrays become per-(node,tile).
//     count_kernel XCD-partitioned like scatter (16-target granule rows are
//     exactly 13 cache lines => single-XCD line ownership).
// ---------------------------------------------------------------------------

#define HID 128
#define TSH 13            // source-tile shift: 8192 nodes/tile
#define NPW 13            // nodes per wave in propagate (8192 waves total)
#define PROP_BLOCKS 2048  // 8192 waves

__device__ __forceinline__ unsigned short f2bf(float f) {
    unsigned int u = __float_as_uint(f);
    unsigned int r = (u + 0x7FFFu + ((u >> 16) & 1u)) >> 16;  // RNE
    return (unsigned short)r;
}
__device__ __forceinline__ unsigned int pack2bf(float lo, float hi) {
    return (unsigned int)f2bf(lo) | ((unsigned int)f2bf(hi) << 16);
}

// --- detect whether edge_index buffer is int64 or int32 --------------------
__global__ void detect_kernel(const unsigned int* __restrict__ w, int* __restrict__ mode, int nwords) {
    __shared__ int any;
    if (threadIdx.x == 0) any = 0;
    __syncthreads();
    for (int i = threadIdx.x * 2 + 1; i < nwords && i < 8192; i += 512) {
        if (w[i] != 0) atomicOr(&any, 1);
    }
    __syncthreads();
    if (threadIdx.x == 0) *mode = any ? 0 : 1;  // 1 => int64 layout
}

__device__ __forceinline__ int load_idx(const void* ei, size_t i, int mode) {
    return mode ? (int)((const long long*)ei)[i] : ((const int*)ei)[i];
}

// --- XCD-partitioned per-(target, source-tile) histogram -------------------
// A 16-target granule's counter rows = 16*NT*4B; for NT=13 that's 832B = 13
// full cache lines => all written by one XCD group.
__global__ __launch_bounds__(256) void count_part_kernel(
    const void* __restrict__ ei, const int* __restrict__ modep,
    int* __restrict__ cnt2, int E, int NT) {
    int g = blockIdx.x & 7;
    int cb = blockIdx.x >> 3;
    int stride = (gridDim.x >> 3) * 256;
    int mode = *modep;
    for (int e = cb * 256 + threadIdx.x; e < E; e += stride) {
        int c = load_idx(ei, (size_t)E + e, mode);
        if (((c >> 4) & 7) != g) continue;
        int r = load_idx(ei, (size_t)e, mode);
        atomicAdd(&cnt2[(size_t)c * NT + (r >> TSH)], 1);
    }
}

// --- scan phase 1: per-2048-chunk sums over N2 = n*NT elements -------------
__global__ __launch_bounds__(256) void scan_partial_kernel(const int* __restrict__ cnt2,
                                                           int* __restrict__ blocksum, int N2) {
    int base = blockIdx.x * 2048 + threadIdx.x * 8;
    int s = 0;
    if (base + 8 <= N2) {
        int4 a = *(const int4*)(cnt2 + base);
        int4 b = *(const int4*)(cnt2 + base + 4);
        s = a.x + a.y + a.z + a.w + b.x + b.y + b.z + b.w;
    } else {
        #pragma unroll
        for (int i = 0; i < 8; ++i) if (base + i < N2) s += cnt2[base + i];
    }
    #pragma unroll
    for (int off = 32; off > 0; off >>= 1) s += __shfl_down(s, off);
    __shared__ int ls[4];
    if ((threadIdx.x & 63) == 0) ls[threadIdx.x >> 6] = s;
    __syncthreads();
    if (threadIdx.x == 0) blocksum[blockIdx.x] = ls[0] + ls[1] + ls[2] + ls[3];
}

// --- scan phase 2: scan block sums (nb2 <= 1024) ---------------------------
__global__ __launch_bounds__(1024) void scan_blocksums_kernel(const int* __restrict__ blocksum,
                                                              int* __restrict__ blockoff,
                                                              int* __restrict__ rowptr2,
                                                              int nb, int N2) {
    __shared__ int s[1024];
    int t = threadIdx.x;
    int own = (t < nb) ? blocksum[t] : 0;
    s[t] = own;
    __syncthreads();
    for (int off = 1; off < 1024; off <<= 1) {
        int v = s[t] + ((t >= off) ? s[t - off] : 0);
        __syncthreads();
        s[t] = v;
        __syncthreads();
    }
    if (t < nb) blockoff[t] = s[t] - own;  // exclusive
    if (t == 1023) rowptr2[N2] = s[1023];  // total
}

// --- scan phase 3: per-element exclusive prefix -> rowptr2, cursor2 --------
__global__ __launch_bounds__(256) void scan_finalize_kernel(const int* __restrict__ cnt2,
                                                            const int* __restrict__ blockoff,
                                                            int* __restrict__ rowptr2,
                                                            int* __restrict__ cursor2, int N2) {
    int t = threadIdx.x;
    int base = blockIdx.x * 2048 + t * 8;
    int v[8];
    int own = 0;
    #pragma unroll
    for (int i = 0; i < 8; ++i) {
        v[i] = (base + i < N2) ? cnt2[base + i] : 0;
        own += v[i];
    }
    __shared__ int s[256];
    s[t] = own;
    __syncthreads();
    for (int off = 1; off < 256; off <<= 1) {
        int x = s[t] + ((t >= off) ? s[t - off] : 0);
        __syncthreads();
        s[t] = x;
        __syncthreads();
    }
    int e = blockoff[blockIdx.x] + s[t] - own;
    #pragma unroll
    for (int i = 0; i < 8; ++i) {
        if (base + i < N2) { rowptr2[base + i] = e; cursor2[base + i] = e; }
        e += v[i];
    }
}

// --- per-node dinv from rowptr2 row sums -----------------------------------
__global__ __launch_bounds__(256) void dinv_kernel(const int* __restrict__ rowptr2,
                                                   float* __restrict__ dinv, int n, int NT) {
    int i = blockIdx.x * 256 + threadIdx.x;
    if (i >= n) return;
    int deg = rowptr2[(size_t)(i + 1) * NT] - rowptr2[(size_t)i * NT];
    dinv[i] = rsqrtf((float)(deg + 1));  // +1 self loop
}

// --- XCD-partitioned direct scatter into (node,tile) segments --------------
__global__ __launch_bounds__(256) void scatter_part_kernel(
    const void* __restrict__ ei, const int* __restrict__ modep,
    int* __restrict__ cursor2, int* __restrict__ edge_src, int E, int NT) {
    int g = blockIdx.x & 7;
    int cb = blockIdx.x >> 3;
    int stride = (gridDim.x >> 3) * 256;
    int mode = *modep;
    for (int e = cb * 256 + threadIdx.x; e < E; e += stride) {
        int c = load_idx(ei, (size_t)E + e, mode);
        if (((c >> 4) & 7) != g) continue;
        int r = load_idx(ei, (size_t)e, mode);
        int pos = atomicAdd(&cursor2[(size_t)c * NT + (r >> TSH)], 1);
        edge_src[pos] = r;
    }
}

// --- GEMM1: h = bf16(x @ W1)   (K=25, W1 staged in LDS) --------------------
__global__ __launch_bounds__(256) void gemm1_kernel(const float* __restrict__ x,
                                                    const float* __restrict__ W,
                                                    unsigned short* __restrict__ h, int n) {
    __shared__ float lw[25 * HID];
    for (int i = threadIdx.x; i < 25 * HID; i += 256) lw[i] = W[i];
    __syncthreads();
    int g = threadIdx.x >> 7, c = threadIdx.x & 127;
    for (int r = blockIdx.x * 2 + g; r < n; r += gridDim.x * 2) {
        const float* xr = x + (size_t)r * 25;
        float acc = 0.f;
        #pragma unroll
        for (int k = 0; k < 25; ++k) acc = fmaf(xr[k], lw[k * HID + c], acc);
        h[(size_t)r * HID + c] = f2bf(acc);
    }
}

// --- propagate, tile-major persistent: each wave owns NPW consecutive nodes,
// register accumulators, sweeps source tiles in order (L2-resident gather).
__global__ __launch_bounds__(256) void propagate_kernel(
    const unsigned short* __restrict__ h, const int* __restrict__ rowptr2,
    const int* __restrict__ edge_src, const float* __restrict__ dinv,
    const float* __restrict__ bias, float* __restrict__ out, int n, int NT) {
    int wid = (blockIdx.x * 256 + threadIdx.x) >> 6;
    int lane = threadIdx.x & 63;
    int node0 = wid * NPW;
    if (node0 >= n) return;
    const unsigned int* hp = (const unsigned int*)h;  // 64 uints per row
    float accx[NPW], accy[NPW];
    #pragma unroll
    for (int k = 0; k < NPW; ++k) { accx[k] = 0.f; accy[k] = 0.f; }

    for (int t = 0; t < NT; ++t) {
        #pragma unroll
        for (int k = 0; k < NPW; ++k) {
            int node = node0 + k;
            if (node < n) {
                size_t ri = (size_t)node * NT + t;
                int beg = rowptr2[ri], end_ = rowptr2[ri + 1];
                for (int b = beg; b < end_; b += 64) {
                    int m = end_ - b; if (m > 64) m = 64;
                    int s = 0; float w = 0.f;
                    if (lane < m) { s = edge_src[b + lane]; w = dinv[s]; }
                    for (int j = 0; j < m; ++j) {
                        int sj = __shfl(s, j);
                        float wj = __shfl(w, j);
                        unsigned int v = hp[(size_t)sj * 64 + lane];
                        accx[k] = fmaf(__uint_as_float(v << 16), wj, accx[k]);
                        accy[k] = fmaf(__uint_as_float(v & 0xffff0000u), wj, accy[k]);
                    }
                }
            }
        }
    }

    float bx = bias[lane * 2], by = bias[lane * 2 + 1];
    #pragma unroll
    for (int k = 0; k < NPW; ++k) {
        int node = node0 + k;
        if (node < n) {
            float dc = dinv[node];
            unsigned int v = hp[(size_t)node * 64 + lane];  // self loop
            float ax = fmaf(__uint_as_float(v << 16), dc, accx[k]);
            float ay = fmaf(__uint_as_float(v & 0xffff0000u), dc, accy[k]);
            ax = fmaxf(fmaf(ax, dc, bx), 0.f);
            ay = fmaxf(fmaf(ay, dc, by), 0.f);
            *(float2*)(out + (size_t)node * HID + lane * 2) = make_float2(ax, ay);
        }
    }
}

// --- BN stats: per-channel sum and sumsq (float4 vectorized) ---------------
__global__ __launch_bounds__(256) void bn_stats_kernel(const float* __restrict__ y,
                                                       float* __restrict__ sum,
                                                       float* __restrict__ sumsq, int n) {
    int c4 = (threadIdx.x & 31) * 4;
    int g = threadIdx.x >> 5;  // 8 row-groups
    float4 s = make_float4(0.f, 0.f, 0.f, 0.f);
    float4 s2 = make_float4(0.f, 0.f, 0.f, 0.f);
    for (int r = blockIdx.x * 8 + g; r < n; r += gridDim.x * 8) {
        float4 v = *(const float4*)(y + (size_t)r * HID + c4);
        s.x += v.x; s.y += v.y; s.z += v.z; s.w += v.w;
        s2.x = fmaf(v.x, v.x, s2.x); s2.y = fmaf(v.y, v.y, s2.y);
        s2.z = fmaf(v.z, v.z, s2.z); s2.w = fmaf(v.w, v.w, s2.w);
    }
    __shared__ float4 ls[256], ls2[256];
    ls[threadIdx.x] = s; ls2[threadIdx.x] = s2;
    __syncthreads();
    if (threadIdx.x < 32) {
        #pragma unroll
        for (int i = 1; i < 8; ++i) {
            float4 a = ls[threadIdx.x + i * 32], b = ls2[threadIdx.x + i * 32];
            s.x += a.x; s.y += a.y; s.z += a.z; s.w += a.w;
            s2.x += b.x; s2.y += b.y; s2.z += b.z; s2.w += b.w;
        }
        atomicAdd(&sum[c4 + 0], s.x);  atomicAdd(&sum[c4 + 1], s.y);
        atomicAdd(&sum[c4 + 2], s.z);  atomicAdd(&sum[c4 + 3], s.w);
        atomicAdd(&sumsq[c4 + 0], s2.x); atomicAdd(&sumsq[c4 + 1], s2.y);
        atomicAdd(&sumsq[c4 + 2], s2.z); atomicAdd(&sumsq[c4 + 3], s2.w);
    }
}

__global__ void bn_finalize_kernel(const float* __restrict__ sum, const float* __restrict__ sumsq,
                                   const float* __restrict__ gamma, const float* __restrict__ beta,
                                   float* __restrict__ scale, float* __restrict__ shift, float inv_n) {
    int c = threadIdx.x;
    float mean = sum[c] * inv_n;
    float var = sumsq[c] * inv_n - mean * mean;
    float sc = gamma[c] * rsqrtf(var + 1e-5f);
    scale[c] = sc;
    shift[c] = beta[c] - mean * sc;
}

// --- GEMM2: h2 = bf16(bn(y1) @ W2)  (K=128), BN fused into tile load -------
__global__ __launch_bounds__(256) void gemm2_kernel(
    const float* __restrict__ y, const float* __restrict__ W,
    const float* __restrict__ scale, const float* __restrict__ shift,
    unsigned short* __restrict__ out, int n) {
    __shared__ float lw[32][HID];       // [k][c] 16KB
    __shared__ float ly[32][132];       // [k][r] 16.5KB (pad: align + bank-free)
    int t = threadIdx.x;
    int base = blockIdx.x * 128;
    int c8 = (t & 15) * 8;   // col start (16 groups x 8 cols)
    int rg = t >> 4;         // 0..15, rows rg*8 .. rg*8+7
    float acc[8][8];
    #pragma unroll
    for (int r = 0; r < 8; ++r)
        #pragma unroll
        for (int c = 0; c < 8; ++c) acc[r][c] = 0.f;

    int sr = t & 127;        // staging row
    int sg = t >> 7;         // 0/1: which half of k
    for (int kc = 0; kc < 4; ++kc) {
        #pragma unroll
        for (int i = 0; i < 16; ++i) {
            int idx = t + i * 256;
            int kk = idx >> 7, cc = idx & 127;
            lw[kk][cc] = W[(size_t)(kc * 32 + kk) * HID + cc];
        }
        int gr = base + sr;
        #pragma unroll
        for (int i = 0; i < 4; ++i) {
            int k0 = (sg * 4 + i) * 4;
            float4 vy = make_float4(0.f, 0.f, 0.f, 0.f);
            if (gr < n) vy = *(const float4*)(y + (size_t)gr * HID + kc * 32 + k0);
            int gk = kc * 32 + k0;
            ly[k0 + 0][sr] = fmaf(vy.x, scale[gk + 0], shift[gk + 0]);
            ly[k0 + 1][sr] = fmaf(vy.y, scale[gk + 1], shift[gk + 1]);
            ly[k0 + 2][sr] = fmaf(vy.z, scale[gk + 2], shift[gk + 2]);
            ly[k0 + 3][sr] = fmaf(vy.w, scale[gk + 3], shift[gk + 3]);
        }
        __syncthreads();
        #pragma unroll
        for (int k = 0; k < 32; ++k) {
            float4 w0 = *(const float4*)&lw[k][c8];
            float4 w1 = *(const float4*)&lw[k][c8 + 4];
            float4 ya = *(const float4*)&ly[k][rg * 8];
            float4 yb = *(const float4*)&ly[k][rg * 8 + 4];
            float yv[8] = {ya.x, ya.y, ya.z, ya.w, yb.x, yb.y, yb.z, yb.w};
            float wv[8] = {w0.x, w0.y, w0.z, w0.w, w1.x, w1.y, w1.z, w1.w};
            #pragma unroll
            for (int r = 0; r < 8; ++r)
                #pragma unroll
                for (int c = 0; c < 8; ++c)
                    acc[r][c] = fmaf(yv[r], wv[c], acc[r][c]);
        }
        __syncthreads();
    }
    #pragma unroll
    for (int r = 0; r < 8; ++r) {
        int gr = base + rg * 8 + r;
        if (gr < n) {
            uint4 p;
            p.x = pack2bf(acc[r][0], acc[r][1]);
            p.y = pack2bf(acc[r][2], acc[r][3]);
            p.z = pack2bf(acc[r][4], acc[r][5]);
            p.w = pack2bf(acc[r][6], acc[r][7]);
            *(uint4*)&out[(size_t)gr * HID + c8] = p;
        }
    }
}

extern "C" void kernel_launch(void* const* d_in, const int* in_sizes, int n_in,
                              void* d_out, int out_size, void* d_ws, size_t ws_size,
                              hipStream_t stream) {
    const float* x     = (const float*)d_in[0];
    const void*  ei    = d_in[1];
    const float* W1    = (const float*)d_in[2];
    const float* b1    = (const float*)d_in[3];
    const float* gamma = (const float*)d_in[4];
    const float* beta  = (const float*)d_in[5];
    const float* W2    = (const float*)d_in[6];
    const float* b2    = (const float*)d_in[7];
    float* out = (float*)d_out;

    const int f_in = 25;
    int n = in_sizes[0] / f_in;
    int E = in_sizes[1] / 2;
    int NT = (n + (1 << TSH) - 1) >> TSH;       // source tiles (13 for n=100k)
    int N2 = n * NT;                             // (node,tile) cells
    int nb2 = (N2 + 2047) / 2048;                // scan blocks (<=1024)

    char* ws = (char*)d_ws;
    size_t off = 0;
    auto alloc = [&](size_t bytes) -> void* {
        void* p = ws + off;
        off += (bytes + 511) & ~(size_t)511;
        return p;
    };
    int*   cnt2     = (int*)alloc((size_t)N2 * 4);
    int*   rowptr2  = (int*)alloc(((size_t)N2 + 1) * 4);
    int*   cursor2  = (int*)alloc((size_t)N2 * 4);
    float* dinv     = (float*)alloc((size_t)n * 4);
    int*   edge_src = (int*)alloc((size_t)E * 4);
    float* bnacc    = (float*)alloc(256 * 4);   // sum[128] ++ sumsq[128]
    float* sclshift = (float*)alloc(256 * 4);   // scale[128] ++ shift[128]
    int*   mode     = (int*)alloc(4);
    int*   blocksum = (int*)alloc((size_t)nb2 * 4);
    int*   blockoff = (int*)alloc((size_t)nb2 * 4);
    unsigned short* h = (unsigned short*)alloc((size_t)n * HID * 2);  // bf16 h1, then h2

    hipMemsetAsync(cnt2, 0, (size_t)N2 * 4, stream);
    hipMemsetAsync(bnacc, 0, 256 * 4, stream);

    detect_kernel<<<1, 256, 0, stream>>>((const unsigned int*)ei, mode, 2 * E);
    count_part_kernel<<<8 * 784, 256, 0, stream>>>(ei, mode, cnt2, E, NT);
    scan_partial_kernel<<<nb2, 256, 0, stream>>>(cnt2, blocksum, N2);
    scan_blocksums_kernel<<<1, 1024, 0, stream>>>(blocksum, blockoff, rowptr2, nb2, N2);
    scan_finalize_kernel<<<nb2, 256, 0, stream>>>(cnt2, blockoff, rowptr2, cursor2, N2);
    dinv_kernel<<<(n + 255) / 256, 256, 0, stream>>>(rowptr2, dinv, n, NT);
    scatter_part_kernel<<<8 * 784, 256, 0, stream>>>(ei, mode, cursor2, edge_src, E, NT);

    // layer 1: h1 = bf16(x@W1) ; y1 = relu(prop(h1) + b1) -> d_out (fp32)
    gemm1_kernel<<<4096, 256, 0, stream>>>(x, W1, h, n);
    propagate_kernel<<<PROP_BLOCKS, 256, 0, stream>>>(h, rowptr2, edge_src, dinv, b1, out, n, NT);

    // batchnorm stats on y1
    bn_stats_kernel<<<512, 256, 0, stream>>>(out, bnacc, bnacc + 128, n);
    bn_finalize_kernel<<<1, 128, 0, stream>>>(bnacc, bnacc + 128, gamma, beta,
                                              sclshift, sclshift + 128, 1.0f / (float)n);

    // layer 2: h2 = bf16(bn(y1)@W2) ; out = relu(prop(h2) + b2)
    gemm2_kernel<<<(n + 127) / 128, 256, 0, stream>>>(out, W2, sclshift, sclshift + 128, h, n);
    propagate_kernel<<<PROP_BLOCKS, 256, 0, stream>>>(h, rowptr2, edge_src, dinv, b2, out, n, NT);
}

// Round 14
// 466.575 us; speedup vs baseline: 2.3180x; 2.3180x over previous
//
#include <hip/hip_runtime.h>
#include <stdint.h>

// ---------------------------------------------------------------------------
// 2-layer GCN: relu(gcn(x,W1,b1)) -> batchnorm -> relu(gcn(.,W2,b2))
// n=100000, E=1.6M, f_in=25, hid=128.
// R2: parallel scan (947 -> 681). R6: gemm2 tile + bf16 h (681 -> 593).
// R10: XCD-partitioned direct scatter (593 -> 546).
// R13 FAILED (546->1081): source-tiling fragmented edge lists to ~1.2
//     edges/segment; per-segment overhead dominated. REVERTED.
// R14: propagate is LATENCY-bound: 1 outstanding gather/wave x ~500cy
//     => ~2.9 TB/s (matches measured 2.3-3.8). Inner loop now 8-way
//     unrolled: 8 independent row-gathers in flight per wave.
// ---------------------------------------------------------------------------

#define HID 128

__device__ __forceinline__ unsigned short f2bf(float f) {
    unsigned int u = __float_as_uint(f);
    unsigned int r = (u + 0x7FFFu + ((u >> 16) & 1u)) >> 16;  // RNE
    return (unsigned short)r;
}
__device__ __forceinline__ unsigned int pack2bf(float lo, float hi) {
    return (unsigned int)f2bf(lo) | ((unsigned int)f2bf(hi) << 16);
}
__device__ __forceinline__ float bflo(unsigned int v) { return __uint_as_float(v << 16); }
__device__ __forceinline__ float bfhi(unsigned int v) { return __uint_as_float(v & 0xffff0000u); }

// --- detect whether edge_index buffer is int64 or int32 --------------------
__global__ void detect_kernel(const unsigned int* __restrict__ w, int* __restrict__ mode, int nwords) {
    __shared__ int any;
    if (threadIdx.x == 0) any = 0;
    __syncthreads();
    for (int i = threadIdx.x * 2 + 1; i < nwords && i < 8192; i += 512) {
        if (w[i] != 0) atomicOr(&any, 1);
    }
    __syncthreads();
    if (threadIdx.x == 0) *mode = any ? 0 : 1;  // 1 => int64 layout
}

__device__ __forceinline__ int load_idx(const void* ei, size_t i, int mode) {
    return mode ? (int)((const long long*)ei)[i] : ((const int*)ei)[i];
}

// --- in-degree histogram (targets = col) -----------------------------------
__global__ void count_kernel(const void* __restrict__ ei, const int* __restrict__ modep,
                             int* __restrict__ cnt, int E) {
    int e = blockIdx.x * blockDim.x + threadIdx.x;
    if (e >= E) return;
    int mode = *modep;
    int c = load_idx(ei, (size_t)E + e, mode);
    atomicAdd(&cnt[c], 1);  // non-returning: HW wave-coalesced
}

// --- scan phase 1: per-256-chunk sums --------------------------------------
__global__ __launch_bounds__(256) void scan_partial_kernel(const int* __restrict__ cnt,
                                                           int* __restrict__ blocksum, int n) {
    int i = blockIdx.x * 256 + threadIdx.x;
    int s = (i < n) ? cnt[i] : 0;
    #pragma unroll
    for (int off = 32; off > 0; off >>= 1) s += __shfl_down(s, off);
    __shared__ int ls[4];
    if ((threadIdx.x & 63) == 0) ls[threadIdx.x >> 6] = s;
    __syncthreads();
    if (threadIdx.x == 0) blocksum[blockIdx.x] = ls[0] + ls[1] + ls[2] + ls[3];
}

// --- scan phase 2: scan block sums (nb <= 1024) ----------------------------
__global__ __launch_bounds__(1024) void scan_blocksums_kernel(const int* __restrict__ blocksum,
                                                              int* __restrict__ blockoff,
                                                              int* __restrict__ rowptr,
                                                              int nb, int n) {
    __shared__ int s[1024];
    int t = threadIdx.x;
    int own = (t < nb) ? blocksum[t] : 0;
    s[t] = own;
    __syncthreads();
    for (int off = 1; off < 1024; off <<= 1) {
        int v = s[t] + ((t >= off) ? s[t - off] : 0);
        __syncthreads();
        s[t] = v;
        __syncthreads();
    }
    if (t < nb) blockoff[t] = s[t] - own;  // exclusive
    if (t == 1023) rowptr[n] = s[1023];    // total
}

// --- scan phase 3: element prefix + dinv + per-node cursor init ------------
__global__ __launch_bounds__(256) void scan_finalize_kernel(const int* __restrict__ cnt,
                                                            const int* __restrict__ blockoff,
                                                            int* __restrict__ rowptr,
                                                            int* __restrict__ cursor,
                                                            float* __restrict__ dinv, int n) {
    int t = threadIdx.x;
    int i = blockIdx.x * 256 + t;
    int own = (i < n) ? cnt[i] : 0;
    __shared__ int s[256];
    s[t] = own;
    __syncthreads();
    for (int off = 1; off < 256; off <<= 1) {
        int x = s[t] + ((t >= off) ? s[t - off] : 0);
        __syncthreads();
        s[t] = x;
        __syncthreads();
    }
    if (i < n) {
        int e0 = blockoff[blockIdx.x] + s[t] - own;
        rowptr[i] = e0;
        cursor[i] = e0;
        dinv[i] = rsqrtf((float)(own + 1));  // +1 self loop
    }
}

// --- XCD-partitioned direct scatter ----------------------------------------
// group g = blockIdx&7 (round-robin => XCD g in practice); group handles
// edges whose target granule (tgt>>4)&7 == g. Each group scans all E edges.
__global__ __launch_bounds__(256) void scatter_part_kernel(
    const void* __restrict__ ei, const int* __restrict__ modep,
    int* __restrict__ cursor, int* __restrict__ edge_src, int E) {
    int g = blockIdx.x & 7;
    int cb = blockIdx.x >> 3;          // chunk index within group
    int nchunks = gridDim.x >> 3;      // blocks per group
    int mode = *modep;
    int stride = nchunks * 256;
    for (int e = cb * 256 + threadIdx.x; e < E; e += stride) {
        int c = load_idx(ei, (size_t)E + e, mode);
        if (((c >> 4) & 7) != g) continue;
        int r = load_idx(ei, (size_t)e, mode);
        int pos = atomicAdd(&cursor[c], 1);
        edge_src[pos] = r;
    }
}

// --- GEMM1: h = bf16(x @ W1)   (K=25, W1 staged in LDS) --------------------
__global__ __launch_bounds__(256) void gemm1_kernel(const float* __restrict__ x,
                                                    const float* __restrict__ W,
                                                    unsigned short* __restrict__ h, int n) {
    __shared__ float lw[25 * HID];
    for (int i = threadIdx.x; i < 25 * HID; i += 256) lw[i] = W[i];
    __syncthreads();
    int g = threadIdx.x >> 7, c = threadIdx.x & 127;
    for (int r = blockIdx.x * 2 + g; r < n; r += gridDim.x * 2) {
        const float* xr = x + (size_t)r * 25;
        float acc = 0.f;
        #pragma unroll
        for (int k = 0; k < 25; ++k) acc = fmaf(xr[k], lw[k * HID + c], acc);
        h[(size_t)r * HID + c] = f2bf(acc);
    }
}

// --- propagation: out[c] = relu(dinv[c]*(sum_e h[src]*dinv[src] + h[c]*dinv[c]) + b)
// 8-way unrolled gather loop: 8 independent row loads in flight per wave.
__global__ __launch_bounds__(256) void propagate_kernel(
    const unsigned short* __restrict__ h, const int* __restrict__ rowptr,
    const int* __restrict__ edge_src, const float* __restrict__ dinv,
    const float* __restrict__ bias, float* __restrict__ out, int n) {
    int wid = (blockIdx.x * 256 + threadIdx.x) >> 6;
    if (wid >= n) return;
    int lane = threadIdx.x & 63;
    int beg = rowptr[wid], end = rowptr[wid + 1];
    float dc = dinv[wid];
    float ax = 0.f, ay = 0.f;
    const unsigned int* hp = (const unsigned int*)h;  // 64 uints per row
    for (int b = beg; b < end; b += 64) {
        int m = end - b; if (m > 64) m = 64;
        int s = 0; float w = 0.f;
        if (lane < m) { s = edge_src[b + lane]; w = dinv[s]; }
        int j = 0;
        for (; j + 8 <= m; j += 8) {
            int s0 = __shfl(s, j + 0), s1 = __shfl(s, j + 1);
            int s2 = __shfl(s, j + 2), s3 = __shfl(s, j + 3);
            int s4 = __shfl(s, j + 4), s5 = __shfl(s, j + 5);
            int s6 = __shfl(s, j + 6), s7 = __shfl(s, j + 7);
            unsigned int v0 = hp[(size_t)s0 * 64 + lane];
            unsigned int v1 = hp[(size_t)s1 * 64 + lane];
            unsigned int v2 = hp[(size_t)s2 * 64 + lane];
            unsigned int v3 = hp[(size_t)s3 * 64 + lane];
            unsigned int v4 = hp[(size_t)s4 * 64 + lane];
            unsigned int v5 = hp[(size_t)s5 * 64 + lane];
            unsigned int v6 = hp[(size_t)s6 * 64 + lane];
            unsigned int v7 = hp[(size_t)s7 * 64 + lane];
            float w0 = __shfl(w, j + 0), w1 = __shfl(w, j + 1);
            float w2 = __shfl(w, j + 2), w3 = __shfl(w, j + 3);
            float w4 = __shfl(w, j + 4), w5 = __shfl(w, j + 5);
            float w6 = __shfl(w, j + 6), w7 = __shfl(w, j + 7);
            ax = fmaf(bflo(v0), w0, ax); ay = fmaf(bfhi(v0), w0, ay);
            ax = fmaf(bflo(v1), w1, ax); ay = fmaf(bfhi(v1), w1, ay);
            ax = fmaf(bflo(v2), w2, ax); ay = fmaf(bfhi(v2), w2, ay);
            ax = fmaf(bflo(v3), w3, ax); ay = fmaf(bfhi(v3), w3, ay);
            ax = fmaf(bflo(v4), w4, ax); ay = fmaf(bfhi(v4), w4, ay);
            ax = fmaf(bflo(v5), w5, ax); ay = fmaf(bfhi(v5), w5, ay);
            ax = fmaf(bflo(v6), w6, ax); ay = fmaf(bfhi(v6), w6, ay);
            ax = fmaf(bflo(v7), w7, ax); ay = fmaf(bfhi(v7), w7, ay);
        }
        for (; j < m; ++j) {
            int sj = __shfl(s, j);
            float wj = __shfl(w, j);
            unsigned int v = hp[(size_t)sj * 64 + lane];
            ax = fmaf(bflo(v), wj, ax);
            ay = fmaf(bfhi(v), wj, ay);
        }
    }
    {   // self loop
        unsigned int v = hp[(size_t)wid * 64 + lane];
        ax = fmaf(bflo(v), dc, ax);
        ay = fmaf(bfhi(v), dc, ay);
    }
    float bx = bias[lane * 2], by = bias[lane * 2 + 1];
    ax = fmaxf(fmaf(ax, dc, bx), 0.f);
    ay = fmaxf(fmaf(ay, dc, by), 0.f);
    *(float2*)(out + (size_t)wid * HID + lane * 2) = make_float2(ax, ay);
}

// --- BN stats: per-channel sum and sumsq -----------------------------------
__global__ __launch_bounds__(256) void bn_stats_kernel(const float* __restrict__ y,
                                                       float* __restrict__ sum,
                                                       float* __restrict__ sumsq, int n) {
    int c = threadIdx.x & 127;
    int g = threadIdx.x >> 7;
    float s = 0.f, s2 = 0.f;
    for (int r = blockIdx.x * 2 + g; r < n; r += gridDim.x * 2) {
        float v = y[(size_t)r * HID + c];
        s += v;
        s2 = fmaf(v, v, s2);
    }
    __shared__ float ls[256], ls2[256];
    ls[threadIdx.x] = s; ls2[threadIdx.x] = s2;
    __syncthreads();
    if (threadIdx.x < 128) {
        atomicAdd(&sum[c], ls[threadIdx.x] + ls[threadIdx.x + 128]);
        atomicAdd(&sumsq[c], ls2[threadIdx.x] + ls2[threadIdx.x + 128]);
    }
}

__global__ void bn_finalize_kernel(const float* __restrict__ sum, const float* __restrict__ sumsq,
                                   const float* __restrict__ gamma, const float* __restrict__ beta,
                                   float* __restrict__ scale, float* __restrict__ shift, float inv_n) {
    int c = threadIdx.x;
    float mean = sum[c] * inv_n;
    float var = sumsq[c] * inv_n - mean * mean;
    float sc = gamma[c] * rsqrtf(var + 1e-5f);
    scale[c] = sc;
    shift[c] = beta[c] - mean * sc;
}

// --- GEMM2: h2 = bf16(bn(y1) @ W2)  (K=128), BN fused into tile load -------
__global__ __launch_bounds__(256) void gemm2_kernel(
    const float* __restrict__ y, const float* __restrict__ W,
    const float* __restrict__ scale, const float* __restrict__ shift,
    unsigned short* __restrict__ out, int n) {
    __shared__ float lw[32][HID];       // [k][c] 16KB
    __shared__ float ly[32][132];       // [k][r] 16.5KB (pad: align + bank-free)
    int t = threadIdx.x;
    int base = blockIdx.x * 128;
    int c8 = (t & 15) * 8;   // col start (16 groups x 8 cols)
    int rg = t >> 4;         // 0..15, rows rg*8 .. rg*8+7
    float acc[8][8];
    #pragma unroll
    for (int r = 0; r < 8; ++r)
        #pragma unroll
        for (int c = 0; c < 8; ++c) acc[r][c] = 0.f;

    int sr = t & 127;        // staging row
    int sg = t >> 7;         // 0/1: which half of k
    for (int kc = 0; kc < 4; ++kc) {
        #pragma unroll
        for (int i = 0; i < 16; ++i) {
            int idx = t + i * 256;
            int kk = idx >> 7, cc = idx & 127;
            lw[kk][cc] = W[(size_t)(kc * 32 + kk) * HID + cc];
        }
        int gr = base + sr;
        #pragma unroll
        for (int i = 0; i < 4; ++i) {
            int k0 = (sg * 4 + i) * 4;
            float4 vy = make_float4(0.f, 0.f, 0.f, 0.f);
            if (gr < n) vy = *(const float4*)(y + (size_t)gr * HID + kc * 32 + k0);
            int gk = kc * 32 + k0;
            ly[k0 + 0][sr] = fmaf(vy.x, scale[gk + 0], shift[gk + 0]);
            ly[k0 + 1][sr] = fmaf(vy.y, scale[gk + 1], shift[gk + 1]);
            ly[k0 + 2][sr] = fmaf(vy.z, scale[gk + 2], shift[gk + 2]);
            ly[k0 + 3][sr] = fmaf(vy.w, scale[gk + 3], shift[gk + 3]);
        }
        __syncthreads();
        #pragma unroll
        for (int k = 0; k < 32; ++k) {
            float4 w0 = *(const float4*)&lw[k][c8];
            float4 w1 = *(const float4*)&lw[k][c8 + 4];
            float4 ya = *(const float4*)&ly[k][rg * 8];
            float4 yb = *(const float4*)&ly[k][rg * 8 + 4];
            float yv[8] = {ya.x, ya.y, ya.z, ya.w, yb.x, yb.y, yb.z, yb.w};
            float wv[8] = {w0.x, w0.y, w0.z, w0.w, w1.x, w1.y, w1.z, w1.w};
            #pragma unroll
            for (int r = 0; r < 8; ++r)
                #pragma unroll
                for (int c = 0; c < 8; ++c)
                    acc[r][c] = fmaf(yv[r], wv[c], acc[r][c]);
        }
        __syncthreads();
    }
    #pragma unroll
    for (int r = 0; r < 8; ++r) {
        int gr = base + rg * 8 + r;
        if (gr < n) {
            uint4 p;
            p.x = pack2bf(acc[r][0], acc[r][1]);
            p.y = pack2bf(acc[r][2], acc[r][3]);
            p.z = pack2bf(acc[r][4], acc[r][5]);
            p.w = pack2bf(acc[r][6], acc[r][7]);
            *(uint4*)&out[(size_t)gr * HID + c8] = p;
        }
    }
}

extern "C" void kernel_launch(void* const* d_in, const int* in_sizes, int n_in,
                              void* d_out, int out_size, void* d_ws, size_t ws_size,
                              hipStream_t stream) {
    const float* x     = (const float*)d_in[0];
    const void*  ei    = d_in[1];
    const float* W1    = (const float*)d_in[2];
    const float* b1    = (const float*)d_in[3];
    const float* gamma = (const float*)d_in[4];
    const float* beta  = (const float*)d_in[5];
    const float* W2    = (const float*)d_in[6];
    const float* b2    = (const float*)d_in[7];
    float* out = (float*)d_out;

    const int f_in = 25;
    int n = in_sizes[0] / f_in;
    int E = in_sizes[1] / 2;
    int nb = (n + 255) >> 8;    // 256-node scan chunks

    char* ws = (char*)d_ws;
    size_t off = 0;
    auto alloc = [&](size_t bytes) -> void* {
        void* p = ws + off;
        off += (bytes + 511) & ~(size_t)511;
        return p;
    };
    int*   cnt        = (int*)alloc((size_t)n * 4);
    int*   rowptr     = (int*)alloc(((size_t)n + 1) * 4);
    int*   cursor     = (int*)alloc((size_t)n * 4);
    float* dinv       = (float*)alloc((size_t)n * 4);
    int*   edge_src   = (int*)alloc((size_t)E * 4);
    float* bnacc      = (float*)alloc(256 * 4);   // sum[128] ++ sumsq[128]
    float* sclshift   = (float*)alloc(256 * 4);   // scale[128] ++ shift[128]
    int*   mode       = (int*)alloc(4);
    int*   blocksum   = (int*)alloc((size_t)nb * 4);
    int*   blockoff   = (int*)alloc((size_t)nb * 4);
    unsigned short* h = (unsigned short*)alloc((size_t)n * HID * 2);  // bf16 h1, then h2

    hipMemsetAsync(cnt, 0, (size_t)n * 4, stream);
    hipMemsetAsync(bnacc, 0, 256 * 4, stream);

    detect_kernel<<<1, 256, 0, stream>>>((const unsigned int*)ei, mode, 2 * E);
    count_kernel<<<(E + 255) / 256, 256, 0, stream>>>(ei, mode, cnt, E);
    scan_partial_kernel<<<nb, 256, 0, stream>>>(cnt, blocksum, n);
    scan_blocksums_kernel<<<1, 1024, 0, stream>>>(blocksum, blockoff, rowptr, nb, n);
    scan_finalize_kernel<<<nb, 256, 0, stream>>>(cnt, blockoff, rowptr, cursor, dinv, n);
    // 8 groups x 784 blocks; consecutive blockIdx -> groups 0..7 (XCD round-robin)
    scatter_part_kernel<<<8 * 784, 256, 0, stream>>>(ei, mode, cursor, edge_src, E);

    // layer 1: h1 = bf16(x@W1) ; y1 = relu(prop(h1) + b1) -> stored in d_out (fp32)
    gemm1_kernel<<<4096, 256, 0, stream>>>(x, W1, h, n);
    propagate_kernel<<<(n + 3) / 4, 256, 0, stream>>>(h, rowptr, edge_src, dinv, b1, out, n);

    // batchnorm stats on y1
    bn_stats_kernel<<<512, 256, 0, stream>>>(out, bnacc, bnacc + 128, n);
    bn_finalize_kernel<<<1, 128, 0, stream>>>(bnacc, bnacc + 128, gamma, beta,
                                              sclshift, sclshift + 128, 1.0f / (float)n);

    // layer 2: h2 = bf16(bn(y1)@W2) ; out = relu(prop(h2) + b2)
    gemm2_kernel<<<(n + 127) / 128, 256, 0, stream>>>(out, W2, sclshift, sclshift + 128, h, n);
    propagate_kernel<<<(n + 3) / 4, 256, 0, stream>>>(h, rowptr, edge_src, dinv, b2, out, n);
}

// Round 15
// 415.011 us; speedup vs baseline: 2.6060x; 1.1242x over previous
//
#include <hip/hip_runtime.h>
#include <stdint.h>

// ---------------------------------------------------------------------------
// 2-layer GCN: relu(gcn(x,W1,b1)) -> batchnorm -> relu(gcn(.,W2,b2))
// n=100000, E=1.6M, f_in=25, hid=128.
// R2: parallel scan (947 -> 681). R6: gemm2 tile + bf16 h (681 -> 593).
// R10: XCD-partitioned direct scatter (593 -> 546).
// R14: 8-deep pipelined propagate gather (546 -> 467).
// R15: gemm2 -> MFMA bf16 (was 94us at 22% of fp32 VALU peak with 3.2M LDS
//     bank conflicts; matrix pipe idle all along). W2 transposed+bf16 once
//     (wt_kernel), gemm2 block stages Wt[128][136] + BN'd y-tile[128][136]
//     bf16 in LDS (69.6KB, 2 blocks/CU, single barrier), 4 waves x 32 rows,
//     64x mfma_f32_16x16x32_bf16 per wave. Frag map: C/D col=lane&15,
//     row=(lane>>4)*4+reg; A/B: 8 contiguous k at (lane>>4)*8.
// ---------------------------------------------------------------------------

#define HID 128

typedef short bf16x8 __attribute__((ext_vector_type(8)));
typedef float f32x4 __attribute__((ext_vector_type(4)));

__device__ __forceinline__ unsigned short f2bf(float f) {
    unsigned int u = __float_as_uint(f);
    unsigned int r = (u + 0x7FFFu + ((u >> 16) & 1u)) >> 16;  // RNE
    return (unsigned short)r;
}
__device__ __forceinline__ unsigned int pack2bf(float lo, float hi) {
    return (unsigned int)f2bf(lo) | ((unsigned int)f2bf(hi) << 16);
}
__device__ __forceinline__ float bflo(unsigned int v) { return __uint_as_float(v << 16); }
__device__ __forceinline__ float bfhi(unsigned int v) { return __uint_as_float(v & 0xffff0000u); }

// --- detect whether edge_index buffer is int64 or int32 --------------------
__global__ void detect_kernel(const unsigned int* __restrict__ w, int* __restrict__ mode, int nwords) {
    __shared__ int any;
    if (threadIdx.x == 0) any = 0;
    __syncthreads();
    for (int i = threadIdx.x * 2 + 1; i < nwords && i < 8192; i += 512) {
        if (w[i] != 0) atomicOr(&any, 1);
    }
    __syncthreads();
    if (threadIdx.x == 0) *mode = any ? 0 : 1;  // 1 => int64 layout
}

__device__ __forceinline__ int load_idx(const void* ei, size_t i, int mode) {
    return mode ? (int)((const long long*)ei)[i] : ((const int*)ei)[i];
}

// --- in-degree histogram (targets = col) -----------------------------------
__global__ void count_kernel(const void* __restrict__ ei, const int* __restrict__ modep,
                             int* __restrict__ cnt, int E) {
    int e = blockIdx.x * blockDim.x + threadIdx.x;
    if (e >= E) return;
    int mode = *modep;
    int c = load_idx(ei, (size_t)E + e, mode);
    atomicAdd(&cnt[c], 1);  // non-returning: HW wave-coalesced
}

// --- scan phase 1: per-256-chunk sums --------------------------------------
__global__ __launch_bounds__(256) void scan_partial_kernel(const int* __restrict__ cnt,
                                                           int* __restrict__ blocksum, int n) {
    int i = blockIdx.x * 256 + threadIdx.x;
    int s = (i < n) ? cnt[i] : 0;
    #pragma unroll
    for (int off = 32; off > 0; off >>= 1) s += __shfl_down(s, off);
    __shared__ int ls[4];
    if ((threadIdx.x & 63) == 0) ls[threadIdx.x >> 6] = s;
    __syncthreads();
    if (threadIdx.x == 0) blocksum[blockIdx.x] = ls[0] + ls[1] + ls[2] + ls[3];
}

// --- scan phase 2: scan block sums (nb <= 1024) ----------------------------
__global__ __launch_bounds__(1024) void scan_blocksums_kernel(const int* __restrict__ blocksum,
                                                              int* __restrict__ blockoff,
                                                              int* __restrict__ rowptr,
                                                              int nb, int n) {
    __shared__ int s[1024];
    int t = threadIdx.x;
    int own = (t < nb) ? blocksum[t] : 0;
    s[t] = own;
    __syncthreads();
    for (int off = 1; off < 1024; off <<= 1) {
        int v = s[t] + ((t >= off) ? s[t - off] : 0);
        __syncthreads();
        s[t] = v;
        __syncthreads();
    }
    if (t < nb) blockoff[t] = s[t] - own;  // exclusive
    if (t == 1023) rowptr[n] = s[1023];    // total
}

// --- scan phase 3: element prefix + dinv + per-node cursor init ------------
__global__ __launch_bounds__(256) void scan_finalize_kernel(const int* __restrict__ cnt,
                                                            const int* __restrict__ blockoff,
                                                            int* __restrict__ rowptr,
                                                            int* __restrict__ cursor,
                                                            float* __restrict__ dinv, int n) {
    int t = threadIdx.x;
    int i = blockIdx.x * 256 + t;
    int own = (i < n) ? cnt[i] : 0;
    __shared__ int s[256];
    s[t] = own;
    __syncthreads();
    for (int off = 1; off < 256; off <<= 1) {
        int x = s[t] + ((t >= off) ? s[t - off] : 0);
        __syncthreads();
        s[t] = x;
        __syncthreads();
    }
    if (i < n) {
        int e0 = blockoff[blockIdx.x] + s[t] - own;
        rowptr[i] = e0;
        cursor[i] = e0;
        dinv[i] = rsqrtf((float)(own + 1));  // +1 self loop
    }
}

// --- XCD-partitioned direct scatter ----------------------------------------
__global__ __launch_bounds__(256) void scatter_part_kernel(
    const void* __restrict__ ei, const int* __restrict__ modep,
    int* __restrict__ cursor, int* __restrict__ edge_src, int E) {
    int g = blockIdx.x & 7;
    int cb = blockIdx.x >> 3;          // chunk index within group
    int nchunks = gridDim.x >> 3;      // blocks per group
    int mode = *modep;
    int stride = nchunks * 256;
    for (int e = cb * 256 + threadIdx.x; e < E; e += stride) {
        int c = load_idx(ei, (size_t)E + e, mode);
        if (((c >> 4) & 7) != g) continue;
        int r = load_idx(ei, (size_t)e, mode);
        int pos = atomicAdd(&cursor[c], 1);
        edge_src[pos] = r;
    }
}

// --- GEMM1: h = bf16(x @ W1)   (K=25, W1 staged in LDS) --------------------
__global__ __launch_bounds__(256) void gemm1_kernel(const float* __restrict__ x,
                                                    const float* __restrict__ W,
                                                    unsigned short* __restrict__ h, int n) {
    __shared__ float lw[25 * HID];
    for (int i = threadIdx.x; i < 25 * HID; i += 256) lw[i] = W[i];
    __syncthreads();
    int g = threadIdx.x >> 7, c = threadIdx.x & 127;
    for (int r = blockIdx.x * 2 + g; r < n; r += gridDim.x * 2) {
        const float* xr = x + (size_t)r * 25;
        float acc = 0.f;
        #pragma unroll
        for (int k = 0; k < 25; ++k) acc = fmaf(xr[k], lw[k * HID + c], acc);
        h[(size_t)r * HID + c] = f2bf(acc);
    }
}

// --- propagation: 8-way unrolled gather loop -------------------------------
__global__ __launch_bounds__(256) void propagate_kernel(
    const unsigned short* __restrict__ h, const int* __restrict__ rowptr,
    const int* __restrict__ edge_src, const float* __restrict__ dinv,
    const float* __restrict__ bias, float* __restrict__ out, int n) {
    int wid = (blockIdx.x * 256 + threadIdx.x) >> 6;
    if (wid >= n) return;
    int lane = threadIdx.x & 63;
    int beg = rowptr[wid], end = rowptr[wid + 1];
    float dc = dinv[wid];
    float ax = 0.f, ay = 0.f;
    const unsigned int* hp = (const unsigned int*)h;  // 64 uints per row
    for (int b = beg; b < end; b += 64) {
        int m = end - b; if (m > 64) m = 64;
        int s = 0; float w = 0.f;
        if (lane < m) { s = edge_src[b + lane]; w = dinv[s]; }
        int j = 0;
        for (; j + 8 <= m; j += 8) {
            int s0 = __shfl(s, j + 0), s1 = __shfl(s, j + 1);
            int s2 = __shfl(s, j + 2), s3 = __shfl(s, j + 3);
            int s4 = __shfl(s, j + 4), s5 = __shfl(s, j + 5);
            int s6 = __shfl(s, j + 6), s7 = __shfl(s, j + 7);
            unsigned int v0 = hp[(size_t)s0 * 64 + lane];
            unsigned int v1 = hp[(size_t)s1 * 64 + lane];
            unsigned int v2 = hp[(size_t)s2 * 64 + lane];
            unsigned int v3 = hp[(size_t)s3 * 64 + lane];
            unsigned int v4 = hp[(size_t)s4 * 64 + lane];
            unsigned int v5 = hp[(size_t)s5 * 64 + lane];
            unsigned int v6 = hp[(size_t)s6 * 64 + lane];
            unsigned int v7 = hp[(size_t)s7 * 64 + lane];
            float w0 = __shfl(w, j + 0), w1 = __shfl(w, j + 1);
            float w2 = __shfl(w, j + 2), w3 = __shfl(w, j + 3);
            float w4 = __shfl(w, j + 4), w5 = __shfl(w, j + 5);
            float w6 = __shfl(w, j + 6), w7 = __shfl(w, j + 7);
            ax = fmaf(bflo(v0), w0, ax); ay = fmaf(bfhi(v0), w0, ay);
            ax = fmaf(bflo(v1), w1, ax); ay = fmaf(bfhi(v1), w1, ay);
            ax = fmaf(bflo(v2), w2, ax); ay = fmaf(bfhi(v2), w2, ay);
            ax = fmaf(bflo(v3), w3, ax); ay = fmaf(bfhi(v3), w3, ay);
            ax = fmaf(bflo(v4), w4, ax); ay = fmaf(bfhi(v4), w4, ay);
            ax = fmaf(bflo(v5), w5, ax); ay = fmaf(bfhi(v5), w5, ay);
            ax = fmaf(bflo(v6), w6, ax); ay = fmaf(bfhi(v6), w6, ay);
            ax = fmaf(bflo(v7), w7, ax); ay = fmaf(bfhi(v7), w7, ay);
        }
        for (; j < m; ++j) {
            int sj = __shfl(s, j);
            float wj = __shfl(w, j);
            unsigned int v = hp[(size_t)sj * 64 + lane];
            ax = fmaf(bflo(v), wj, ax);
            ay = fmaf(bfhi(v), wj, ay);
        }
    }
    {   // self loop
        unsigned int v = hp[(size_t)wid * 64 + lane];
        ax = fmaf(bflo(v), dc, ax);
        ay = fmaf(bfhi(v), dc, ay);
    }
    float bx = bias[lane * 2], by = bias[lane * 2 + 1];
    ax = fmaxf(fmaf(ax, dc, bx), 0.f);
    ay = fmaxf(fmaf(ay, dc, by), 0.f);
    *(float2*)(out + (size_t)wid * HID + lane * 2) = make_float2(ax, ay);
}

// --- BN stats: per-channel sum and sumsq -----------------------------------
__global__ __launch_bounds__(256) void bn_stats_kernel(const float* __restrict__ y,
                                                       float* __restrict__ sum,
                                                       float* __restrict__ sumsq, int n) {
    int c = threadIdx.x & 127;
    int g = threadIdx.x >> 7;
    float s = 0.f, s2 = 0.f;
    for (int r = blockIdx.x * 2 + g; r < n; r += gridDim.x * 2) {
        float v = y[(size_t)r * HID + c];
        s += v;
        s2 = fmaf(v, v, s2);
    }
    __shared__ float ls[256], ls2[256];
    ls[threadIdx.x] = s; ls2[threadIdx.x] = s2;
    __syncthreads();
    if (threadIdx.x < 128) {
        atomicAdd(&sum[c], ls[threadIdx.x] + ls[threadIdx.x + 128]);
        atomicAdd(&sumsq[c], ls2[threadIdx.x] + ls2[threadIdx.x + 128]);
    }
}

__global__ void bn_finalize_kernel(const float* __restrict__ sum, const float* __restrict__ sumsq,
                                   const float* __restrict__ gamma, const float* __restrict__ beta,
                                   float* __restrict__ scale, float* __restrict__ shift, float inv_n) {
    int c = threadIdx.x;
    float mean = sum[c] * inv_n;
    float var = sumsq[c] * inv_n - mean * mean;
    float sc = gamma[c] * rsqrtf(var + 1e-5f);
    scale[c] = sc;
    shift[c] = beta[c] - mean * sc;
}

// --- W2 transpose + bf16 cast: Wt[c][k] = bf16(W2[k][c]) -------------------
__global__ __launch_bounds__(256) void wt_kernel(const float* __restrict__ W,
                                                 unsigned short* __restrict__ Wt) {
    int idx = blockIdx.x * 256 + threadIdx.x;
    int c = idx >> 7, k = idx & 127;
    Wt[c * 128 + k] = f2bf(W[k * 128 + c]);
}

// --- GEMM2 via MFMA: h2 = bf16(bn(y1) @ W2), K=128 -------------------------
// Block: 128 rows x 128 cols, 4 waves x (32 rows x 128 cols).
// LDS: whole Wt (bf16, [128][136]) + BN'd y tile (bf16, [128][136]); 1 barrier.
__global__ __launch_bounds__(256) void gemm2_mfma_kernel(
    const float* __restrict__ y, const unsigned short* __restrict__ Wt,
    const float* __restrict__ scale, const float* __restrict__ shift,
    unsigned short* __restrict__ out, int n) {
    __shared__ unsigned short lwt[128 * 136];
    __shared__ unsigned short ly[128 * 136];
    int t = threadIdx.x;
    int base = blockIdx.x * 128;

    // stage Wt: 128 rows x 128 bf16 (64 uints/row), coalesced; LDS stride 68 uints
    {
        const unsigned int* w32 = (const unsigned int*)Wt;
        unsigned int* l32 = (unsigned int*)lwt;
        #pragma unroll
        for (int i = 0; i < 32; ++i) {
            int idx = t + i * 256;
            int r = idx >> 6, cp = idx & 63;
            l32[r * 68 + cp] = w32[r * 64 + cp];
        }
    }
    // stage y tile with BN + bf16 cvt: 2 threads/row, 64 k each
    {
        int r = t >> 1, hh = t & 1;
        int gr = base + r;
        unsigned int* l32 = (unsigned int*)ly;
        const float4* yrow = (const float4*)(y + (size_t)gr * HID + hh * 64);
        #pragma unroll
        for (int j = 0; j < 16; ++j) {
            float4 v = make_float4(0.f, 0.f, 0.f, 0.f);
            if (gr < n) v = yrow[j];
            int gk = hh * 64 + j * 4;
            float a0 = fmaf(v.x, scale[gk + 0], shift[gk + 0]);
            float a1 = fmaf(v.y, scale[gk + 1], shift[gk + 1]);
            float a2 = fmaf(v.z, scale[gk + 2], shift[gk + 2]);
            float a3 = fmaf(v.w, scale[gk + 3], shift[gk + 3]);
            l32[r * 68 + hh * 32 + j * 2 + 0] = pack2bf(a0, a1);
            l32[r * 68 + hh * 32 + j * 2 + 1] = pack2bf(a2, a3);
        }
    }
    __syncthreads();

    int w = t >> 6, lane = t & 63;
    int li = lane & 15, lg = lane >> 4;
    f32x4 acc[2][8];
    #pragma unroll
    for (int a = 0; a < 2; ++a)
        #pragma unroll
        for (int b = 0; b < 8; ++b) acc[a][b] = (f32x4){0.f, 0.f, 0.f, 0.f};

    #pragma unroll
    for (int ks = 0; ks < 4; ++ks) {
        int kb = ks * 32 + lg * 8;
        bf16x8 af[2], bfr[8];
        #pragma unroll
        for (int rt = 0; rt < 2; ++rt)
            af[rt] = *(const bf16x8*)&ly[(w * 32 + rt * 16 + li) * 136 + kb];
        #pragma unroll
        for (int cf = 0; cf < 8; ++cf)
            bfr[cf] = *(const bf16x8*)&lwt[(cf * 16 + li) * 136 + kb];
        #pragma unroll
        for (int rt = 0; rt < 2; ++rt)
            #pragma unroll
            for (int cf = 0; cf < 8; ++cf)
                acc[rt][cf] = __builtin_amdgcn_mfma_f32_16x16x32_bf16(
                    af[rt], bfr[cf], acc[rt][cf], 0, 0, 0);
    }

    // epilogue: D row = (lane>>4)*4 + reg, col = cf*16 + (lane&15)
    #pragma unroll
    for (int rt = 0; rt < 2; ++rt) {
        #pragma unroll
        for (int reg = 0; reg < 4; ++reg) {
            int gr = base + w * 32 + rt * 16 + lg * 4 + reg;
            if (gr < n) {
                #pragma unroll
                for (int cf = 0; cf < 8; ++cf)
                    out[(size_t)gr * HID + cf * 16 + li] = f2bf(acc[rt][cf][reg]);
            }
        }
    }
}

extern "C" void kernel_launch(void* const* d_in, const int* in_sizes, int n_in,
                              void* d_out, int out_size, void* d_ws, size_t ws_size,
                              hipStream_t stream) {
    const float* x     = (const float*)d_in[0];
    const void*  ei    = d_in[1];
    const float* W1    = (const float*)d_in[2];
    const float* b1    = (const float*)d_in[3];
    const float* gamma = (const float*)d_in[4];
    const float* beta  = (const float*)d_in[5];
    const float* W2    = (const float*)d_in[6];
    const float* b2    = (const float*)d_in[7];
    float* out = (float*)d_out;

    const int f_in = 25;
    int n = in_sizes[0] / f_in;
    int E = in_sizes[1] / 2;
    int nb = (n + 255) >> 8;    // 256-node scan chunks

    char* ws = (char*)d_ws;
    size_t off = 0;
    auto alloc = [&](size_t bytes) -> void* {
        void* p = ws + off;
        off += (bytes + 511) & ~(size_t)511;
        return p;
    };
    int*   cnt        = (int*)alloc((size_t)n * 4);
    int*   rowptr     = (int*)alloc(((size_t)n + 1) * 4);
    int*   cursor     = (int*)alloc((size_t)n * 4);
    float* dinv       = (float*)alloc((size_t)n * 4);
    int*   edge_src   = (int*)alloc((size_t)E * 4);
    float* bnacc      = (float*)alloc(256 * 4);   // sum[128] ++ sumsq[128]
    float* sclshift   = (float*)alloc(256 * 4);   // scale[128] ++ shift[128]
    int*   mode       = (int*)alloc(4);
    int*   blocksum   = (int*)alloc((size_t)nb * 4);
    int*   blockoff   = (int*)alloc((size_t)nb * 4);
    unsigned short* Wt = (unsigned short*)alloc(128 * 128 * 2);  // bf16 W2^T
    unsigned short* h  = (unsigned short*)alloc((size_t)n * HID * 2);  // bf16 h1/h2

    hipMemsetAsync(cnt, 0, (size_t)n * 4, stream);
    hipMemsetAsync(bnacc, 0, 256 * 4, stream);

    detect_kernel<<<1, 256, 0, stream>>>((const unsigned int*)ei, mode, 2 * E);
    count_kernel<<<(E + 255) / 256, 256, 0, stream>>>(ei, mode, cnt, E);
    scan_partial_kernel<<<nb, 256, 0, stream>>>(cnt, blocksum, n);
    scan_blocksums_kernel<<<1, 1024, 0, stream>>>(blocksum, blockoff, rowptr, nb, n);
    scan_finalize_kernel<<<nb, 256, 0, stream>>>(cnt, blockoff, rowptr, cursor, dinv, n);
    scatter_part_kernel<<<8 * 784, 256, 0, stream>>>(ei, mode, cursor, edge_src, E);

    // layer 1: h1 = bf16(x@W1) ; y1 = relu(prop(h1) + b1) -> d_out (fp32)
    gemm1_kernel<<<4096, 256, 0, stream>>>(x, W1, h, n);
    propagate_kernel<<<(n + 3) / 4, 256, 0, stream>>>(h, rowptr, edge_src, dinv, b1, out, n);

    // batchnorm stats on y1
    bn_stats_kernel<<<512, 256, 0, stream>>>(out, bnacc, bnacc + 128, n);
    bn_finalize_kernel<<<1, 128, 0, stream>>>(bnacc, bnacc + 128, gamma, beta,
                                              sclshift, sclshift + 128, 1.0f / (float)n);

    // layer 2: h2 = bf16(bn(y1)@W2) via MFMA ; out = relu(prop(h2) + b2)
    wt_kernel<<<64, 256, 0, stream>>>(W2, Wt);
    gemm2_mfma_kernel<<<(n + 127) / 128, 256, 0, stream>>>(out, Wt, sclshift, sclshift + 128, h, n);
    propagate_kernel<<<(n + 3) / 4, 256, 0, stream>>>(h, rowptr, edge_src, dinv, b2, out, n);
}